// Round 8
// baseline (38.002 us; speedup 1.0000x reference)
//
#include <hip/hip_runtime.h>

// Problem constants (fixed by the reference)
#define NTOT 512   // N
#define NH   448   // N - K (identity head)
#define KK   64    // K (solved tail rows)
#define NL   30688 // strictly-lower entries in last K rows
#define DD   16    // domains
#define BB   1024  // batch
#define SLICES 16  // apply blocks per domain
#define MAXG 4     // samples per group iteration
#define LISTCAP 1024
#define BC   128   // columns per buildW block (4 blocks/domain)
#define NQ   (KK / 4)

// ws layout (bytes):
//   [0,64)            counts[16] (int)
//   [1024, 1024+64K)  lists[16][1024] (int)
//   [66560, +2MB)     Wq: [dom][q][r][k] f32, q=c>>2, k=c&3 (c=column, r=row)
#define WS_LISTS_OFF 1024
#define WS_W_OFF     66560

// W_d = (I-U_d)^{-1} [T_d | diag(s_d)] (64x512); z_tail[b] = W_{d_b} @ eps[b].
// L_emb[dom] row m: T[m][0:448] at rb(m)=m*448+m(m-1)/2, then U[m][0:m] at rb+448.
// buildW: thread = column; history w[0..63] lives QUAD-PACKED IN LDS (h4), the
// thread's own private slot -> no spill (r7's killer), no cross-thread sync,
// one conflict-free ds_read_b128 per 16 MACs. U read as wave-uniform broadcasts.
// XCD locality: buildW bid = cb*16+dom, apply bid = slice*16+dom -> XCD dom%8.

// ---------- Kernel A: 64 buildW blocks + 16 scan blocks ----------
__global__ __launch_bounds__(128)
void fvae_prep(const int*   __restrict__ dom_idx,  // [B]
               const float* __restrict__ L_emb,    // [16, NL]
               const float* __restrict__ S_emb,    // [16, 64]
               float*       __restrict__ ws)
{
    const int bid = blockIdx.x;
    const int tid = threadIdx.x;

    if (bid >= 64) {
        // ---- ballot-rank scan for domain bid-64 (wave 0; loads prefetched)
        if (tid < 64) {
            const int dom = bid - 64;
            int* counts = (int*)ws;
            int* lists  = (int*)((char*)ws + WS_LISTS_OFF) + dom * LISTCAP;
            int dm[BB / 64];
            #pragma unroll
            for (int t = 0; t < BB / 64; ++t) dm[t] = dom_idx[t * 64 + tid];
            int base = 0;
            #pragma unroll
            for (int t = 0; t < BB / 64; ++t) {
                const unsigned long long mt = __ballot(dm[t] == dom);
                if (dm[t] == dom) {
                    const int rank = base + __popcll(mt & ((1ull << tid) - 1ull));
                    lists[rank] = t * 64 + tid;
                }
                base += __popcll(mt);
            }
            if (tid == 0) counts[dom] = base;
        }
        return;
    }

    // ---- buildW: bid = cb*16 + dom; this block owns columns [cb*128, cb*128+128)
    const int dom = bid & 15;
    const int cb  = bid >> 4;
    const int c   = cb * BC + tid;     // this thread's column (0..511)
    float* __restrict__ Wd = (float*)((char*)ws + WS_W_OFF) + (size_t)dom * (NTOT * KK);

    if (dom == 0) {                    // W = [0 | I], coalesced direct store
        for (int idx = tid; idx < 32 * KK * 4; idx += BC) {
            const int ql = idx >> 8, r = (idx >> 2) & 63, k = idx & 3;
            const int col = (cb * 32 + ql) * 4 + k;
            Wd[(cb * 32 + ql) * 256 + r * 4 + k] = (col - NH == r) ? 1.f : 0.f;
        }
        return;
    }

    __shared__ float Uq[KK * KK];      // [r][m] row-major, zero-padded (16 KB)
    __shared__ float h4[NQ][BC][4];    // per-thread history, quad-packed (32 KB)

    const float* __restrict__ Ld = L_emb + (size_t)dom * NL;

    // stage U coalesced, zero-padded
    for (int idx = tid; idx < KK * KK; idx += BC) {
        const int r = idx >> 6, m = idx & 63;
        Uq[idx] = (m < r) ? Ld[r * NH + (r * (r - 1)) / 2 + NH + m] : 0.f;
    }
    __syncthreads();

    // rhs for row r, column c (lane-contiguous global load when c < NH)
    const bool inT = (c < NH);
    const int  k0  = c - NH;
    #define RHS(r) (inT ? Ld[(r) * NH + ((r) * ((r) - 1)) / 2 + c] \
                        : ((k0 == (r)) ? S_emb[dom * KK + (r)] : 0.f))

    // software-pipelined blocked forward substitution (4 rows per quad)
    float n0 = RHS(0), n1 = RHS(1), n2 = RHS(2), n3 = RHS(3);
    for (int rq = 0; rq < NQ; ++rq) {
        const int r0 = rq * 4;
        float a0 = n0, a1 = n1, a2 = n2, a3 = n3;
        if (rq + 1 < NQ) {             // prefetch next quad's rhs (hides L2 latency)
            n0 = RHS(r0 + 4); n1 = RHS(r0 + 5); n2 = RHS(r0 + 6); n3 = RHS(r0 + 7);
        }
        for (int m4 = 0; m4 < rq; ++m4) {          // inter-quad accumulation
            const float4 hv = *(const float4*)h4[m4][tid];            // own history
            const float4 u0 = *(const float4*)&Uq[(r0    ) * 64 + m4 * 4]; // bcast
            const float4 u1 = *(const float4*)&Uq[(r0 + 1) * 64 + m4 * 4];
            const float4 u2 = *(const float4*)&Uq[(r0 + 2) * 64 + m4 * 4];
            const float4 u3 = *(const float4*)&Uq[(r0 + 3) * 64 + m4 * 4];
            a0 += u0.x * hv.x + u0.y * hv.y + u0.z * hv.z + u0.w * hv.w;
            a1 += u1.x * hv.x + u1.y * hv.y + u1.z * hv.z + u1.w * hv.w;
            a2 += u2.x * hv.x + u2.y * hv.y + u2.z * hv.z + u2.w * hv.w;
            a3 += u3.x * hv.x + u3.y * hv.y + u3.z * hv.z + u3.w * hv.w;
        }
        // in-quad triangular (wave-uniform broadcasts)
        a1 += Uq[(r0 + 1) * 64 + r0] * a0;
        a2 += Uq[(r0 + 2) * 64 + r0] * a0 + Uq[(r0 + 2) * 64 + r0 + 1] * a1;
        a3 += Uq[(r0 + 3) * 64 + r0] * a0 + Uq[(r0 + 3) * 64 + r0 + 1] * a1
            + Uq[(r0 + 3) * 64 + r0 + 2] * a2;
        float4 hw; hw.x = a0; hw.y = a1; hw.z = a2; hw.w = a3;
        *(float4*)h4[rq][tid] = hw;
    }
    #undef RHS
    __syncthreads();

    // cooperative coalesced store: block region = q in [cb*32, cb*32+32)
    for (int idx = tid; idx < 32 * KK * 4; idx += BC) {
        const int ql = idx >> 8, r = (idx >> 2) & 63, k = idx & 3;
        const int cl = ql * 4 + k;                  // local column 0..127
        Wd[(cb * 32 + ql) * 256 + r * 4 + k] = h4[r >> 2][cl][r & 3];
    }
}

// ---------- Kernel B: grouped matvec, 4 samples share every W load (r6-proven) ----------
__global__ __launch_bounds__(256)
void fvae_apply(const float* __restrict__ eps,      // [B,512]
                const float* __restrict__ bias_ns,  // [16, 64]
                const float* __restrict__ bias_sh,  // [448]
                const float* __restrict__ ws,
                float*       __restrict__ out)      // [B,512]
{
    const int dom   = blockIdx.x & 15;   // XCD dom%8, matches buildW writers
    const int slice = blockIdx.x >> 4;
    const int tid   = threadIdx.x;
    const int w     = tid >> 6;
    const int l     = tid & 63;

    __shared__ float eps_s[MAXG][NTOT];
    __shared__ float part_s[4][MAXG][KK];
    __shared__ int   idx_s[MAXG];

    const int*   counts = (const int*)ws;
    const int*   lists  = (const int*)((const char*)ws + WS_LISTS_OFF) + dom * LISTCAP;
    const float* __restrict__ Wd =
        (const float*)((const char*)ws + WS_W_OFF) + (size_t)dom * (NTOT * KK);

    const int cnt     = counts[dom];
    const int G_total = (cnt > slice) ? (cnt - 1 - slice) / SLICES + 1 : 0;
    if (G_total == 0) return;

    for (int s0 = 0; s0 < G_total; s0 += MAXG) {
        const int Gc = min(MAXG, G_total - s0);
        if (tid < Gc) idx_s[tid] = lists[slice + (s0 + tid) * SLICES];
        __syncthreads();

        for (int v = tid; v < Gc * (NTOT / 4); v += 256) {   // stage eps (float4)
            const int g = v >> 7, q = v & 127;
            *(float4*)&eps_s[g][q * 4] =
                *(const float4*)(eps + (size_t)idx_s[g] * NTOT + q * 4);
        }
        __syncthreads();

        for (int v = tid; v < Gc * (NH / 4); v += 256) {     // head + bias_sh
            const int g = v / 112, q = v - g * 112;
            const float4 e  = *(const float4*)&eps_s[g][q * 4];
            const float4 bs = *(const float4*)(bias_sh + q * 4);
            float4 o; o.x = e.x + bs.x; o.y = e.y + bs.y;
            o.z = e.z + bs.z; o.w = e.w + bs.w;
            *(float4*)(out + (size_t)idx_s[g] * NTOT + q * 4) = o;
        }

        float acc[MAXG];
        #pragma unroll
        for (int g = 0; g < MAXG; ++g) acc[g] = 0.f;
        #pragma unroll
        for (int i = 0; i < 32; ++i) {
            const int q = i * 4 + w;
            const float4 Wv = *(const float4*)(Wd + q * 256 + l * 4);  // 1KB/wave
            #pragma unroll
            for (int g = 0; g < MAXG; ++g) {
                const float4 e = *(const float4*)&eps_s[g][q * 4];     // broadcast
                acc[g] += Wv.x * e.x + Wv.y * e.y + Wv.z * e.z + Wv.w * e.w;
            }
        }
        #pragma unroll
        for (int g = 0; g < MAXG; ++g) part_s[w][g][l] = acc[g];
        __syncthreads();

        if (tid < MAXG * KK) {
            const int g = tid >> 6, r = tid & 63;
            if (g < Gc) {
                const float z = part_s[0][g][r] + part_s[1][g][r]
                              + part_s[2][g][r] + part_s[3][g][r];
                out[(size_t)idx_s[g] * NTOT + NH + r] = z + bias_ns[dom * KK + r];
            }
        }
        __syncthreads();
    }
}

extern "C" void kernel_launch(void* const* d_in, const int* in_sizes, int n_in,
                              void* d_out, int out_size, void* d_ws, size_t ws_size,
                              hipStream_t stream) {
    const float* eps     = (const float*)d_in[0];
    const int*   dom     = (const int*)  d_in[1];
    const float* L_emb   = (const float*)d_in[2];
    const float* S_emb   = (const float*)d_in[3];
    const float* bias_ns = (const float*)d_in[4];
    const float* bias_sh = (const float*)d_in[5];
    float* out = (float*)d_out;
    float* ws  = (float*)d_ws;

    fvae_prep <<<dim3(64 + DD),     dim3(128), 0, stream>>>(dom, L_emb, S_emb, ws);
    fvae_apply<<<dim3(DD * SLICES), dim3(256), 0, stream>>>(eps, bias_ns, bias_sh,
                                                            ws, out);
}

// Round 9
// 17.691 us; speedup vs baseline: 2.1482x; 2.1482x over previous
//
#include <hip/hip_runtime.h>

// Problem constants (fixed by the reference)
#define NTOT 512   // N
#define NH   448   // N - K (identity head)
#define KK   64    // K (solved tail rows)
#define NL   30688 // strictly-lower entries in last K rows
#define DD   16    // domains

// z = F_d eps, F_d = (I-L)^{-1} S  <=>  (I-L) z = S eps.
// Head rows: z_j = eps_j + bias_sh. Tail rows 448+r:
//   y_r = s_r*eps_{448+r} + T_r . eps[0:448];  z_tail = (I-U)^{-1} y.
// L_emb[dom] row m: T[m][0:448] at m*448+m(m-1)/2, then U[m][0:m] at +448.
// One block per sample (1024 blocks = 4/CU): max block-parallelism (r1-proven).
// Fixes vs r1: U staged COALESCED to LDS (kills the 4K uncoalesced line
// transactions/block in phase 3), phase 2 in static 4-row batches (28
// independent coalesced loads in flight) with r4's merged 10-shfl reduce.
__global__ __launch_bounds__(256, 4)
void fvae_fused(const float* __restrict__ eps,      // [B,512]
                const int*   __restrict__ dom_idx,  // [B]
                const float* __restrict__ L_emb,    // [16, NL]
                const float* __restrict__ S_emb,    // [16, 64]
                const float* __restrict__ bias_ns,  // [16, 64]
                const float* __restrict__ bias_sh,  // [448]
                float*       __restrict__ out)      // [B,512]
{
    const int b    = blockIdx.x;
    const int tid  = threadIdx.x;
    const int wave = tid >> 6;
    const int lane = tid & 63;

    __shared__ float eps_s[NTOT];
    __shared__ float y_s[KK];
    __shared__ float U_s[(KK * (KK - 1)) / 2];   // packed strictly-lower (7.9 KB)

    const int dom = dom_idx[b];
    const float* __restrict__ epsb = eps + (size_t)b * NTOT;
    float*       __restrict__ outb = out + (size_t)b * NTOT;
    const float* __restrict__ Ld   = L_emb + (size_t)dom * NL;

    // ---- stage eps (all threads, one float2 each, coalesced)
    *(float2*)&eps_s[tid * 2] = *(const float2*)(epsb + tid * 2);

    // ---- stage packed U coalesced: row r contiguous, r lanes (waves 1-3)
    if (dom != 0 && wave != 0) {
        for (int r = wave; r < KK; r += 3)           // r starts 1,2,3 -> covers 1..63
            if (lane < r)
                U_s[(r * (r - 1)) / 2 + lane] =
                    Ld[r * NH + (r * (r - 1)) / 2 + NH + lane];
    }
    __syncthreads();

    // ---- head: out[:,0:448] = eps + bias_sh (float4, coalesced)
    if (tid < NH / 4) {
        const float4 e  = *(const float4*)&eps_s[tid * 4];
        const float4 bs = *(const float4*)(bias_sh + tid * 4);
        float4 o; o.x = e.x + bs.x; o.y = e.y + bs.y;
        o.z = e.z + bs.z; o.w = e.w + bs.w;
        *(float4*)(outb + tid * 4) = o;
    }

    if (dom != 0) {
        // ---- hoist eps into registers (bank-conflict-free: stride 64 = 2-way)
        float er[7];
        #pragma unroll
        for (int k = 0; k < 7; ++k) er[k] = eps_s[lane + 64 * k];

        // ---- phase 2: wave owns rows [wave*16, wave*16+16), 4 static batches
        #pragma unroll
        for (int bt = 0; bt < 4; ++bt) {
            const int r0 = wave * 16 + bt * 4;
            // 4 rows x 7 coalesced loads, all independent -> deep pipeline
            float a0, a1, a2, a3;
            {
                const float* __restrict__ T0 = Ld + (r0    ) * NH + ((r0    ) * (r0 - 1)) / 2;
                const float* __restrict__ T1 = Ld + (r0 + 1) * NH + ((r0 + 1) * (r0    )) / 2;
                const float* __restrict__ T2 = Ld + (r0 + 2) * NH + ((r0 + 2) * (r0 + 1)) / 2;
                const float* __restrict__ T3 = Ld + (r0 + 3) * NH + ((r0 + 3) * (r0 + 2)) / 2;
                a0 = T0[lane]*er[0] + T0[lane+64]*er[1] + T0[lane+128]*er[2]
                   + T0[lane+192]*er[3] + T0[lane+256]*er[4] + T0[lane+320]*er[5]
                   + T0[lane+384]*er[6];
                a1 = T1[lane]*er[0] + T1[lane+64]*er[1] + T1[lane+128]*er[2]
                   + T1[lane+192]*er[3] + T1[lane+256]*er[4] + T1[lane+320]*er[5]
                   + T1[lane+384]*er[6];
                a2 = T2[lane]*er[0] + T2[lane+64]*er[1] + T2[lane+128]*er[2]
                   + T2[lane+192]*er[3] + T2[lane+256]*er[4] + T2[lane+320]*er[5]
                   + T2[lane+384]*er[6];
                a3 = T3[lane]*er[0] + T3[lane+64]*er[1] + T3[lane+128]*er[2]
                   + T3[lane+192]*er[3] + T3[lane+256]*er[4] + T3[lane+320]*er[5]
                   + T3[lane+384]*er[6];
            }
            // merged butterfly reduce (r4-verified): lane g<4 gets sum of a_g
            a0 += __shfl_xor(a0, 1);  a1 += __shfl_xor(a1, 1);
            a2 += __shfl_xor(a2, 1);  a3 += __shfl_xor(a3, 1);
            float c0 = (lane & 1) ? a1 : a0;
            float c1 = (lane & 1) ? a3 : a2;
            c0 += __shfl_xor(c0, 2);  c1 += __shfl_xor(c1, 2);
            float dsum = (lane & 2) ? c1 : c0;
            dsum += __shfl_xor(dsum, 4);
            dsum += __shfl_xor(dsum, 8);
            dsum += __shfl_xor(dsum, 16);
            dsum += __shfl_xor(dsum, 32);
            if (lane < 4) {
                const int r = r0 + lane;
                y_s[r] = dsum + S_emb[dom * KK + r] * eps_s[NH + r];
            }
        }
        __syncthreads();

        // ---- phase 3: wave 0, 63-step chain; U from LDS (t[] preloaded, indep)
        if (wave == 0) {
            const int m  = lane;
            const int tb = (m * (m - 1)) / 2;
            float t[KK - 1];
            #pragma unroll
            for (int r = 0; r < KK - 1; ++r)
                t[r] = (r < m) ? U_s[tb + r] : 0.f;
            float z = y_s[m];
            #pragma unroll
            for (int r = 0; r < KK - 1; ++r)
                z += t[r] * __shfl(z, r);            // lane r's z final by step r
            outb[NH + m] = z + bias_ns[dom * KK + m];
        }
    } else {
        // ---- domain 0: L=0, S=I -> z_tail = eps_tail
        if (wave == 0)
            outb[NH + lane] = eps_s[NH + lane] + bias_ns[lane];
    }
}

extern "C" void kernel_launch(void* const* d_in, const int* in_sizes, int n_in,
                              void* d_out, int out_size, void* d_ws, size_t ws_size,
                              hipStream_t stream) {
    const float* eps     = (const float*)d_in[0];
    const int*   dom     = (const int*)  d_in[1];
    const float* L_emb   = (const float*)d_in[2];
    const float* S_emb   = (const float*)d_in[3];
    const float* bias_ns = (const float*)d_in[4];
    const float* bias_sh = (const float*)d_in[5];
    float* out = (float*)d_out;

    const int B = in_sizes[0] / NTOT;   // 1024
    fvae_fused<<<dim3(B), dim3(256), 0, stream>>>(eps, dom, L_emb, S_emb,
                                                  bias_ns, bias_sh, out);
}

// Round 10
// 17.289 us; speedup vs baseline: 2.1980x; 1.0232x over previous
//
#include <hip/hip_runtime.h>

// Problem constants (fixed by the reference)
#define NTOT 512   // N
#define NH   448   // N - K (identity head)
#define KK   64    // K (solved tail rows)
#define NL   30688 // strictly-lower entries in last K rows
#define DD   16    // domains

// z = F_d eps, F_d = (I-L)^{-1} S  <=>  (I-L) z = S eps.
// Head rows: z_j = eps_j + bias_sh. Tail rows 448+r:
//   y_r = s_r*eps_{448+r} + T_r . eps[0:448];  z_tail = (I-U)^{-1} y.
// L_emb[dom] row m: T[m][0:448] at m*448+m(m-1)/2, then U[m][0:m] at +448.
// One block per sample (r9-proven). r10 changes: no eps LDS (er[] loaded
// direct from global, coalesced, issued at kernel top and consumed after the
// barrier -> latency hidden under U-staging); no t[63] register preload
// (phase-3 reads U_s directly; ds_read addresses are chain-independent so
// they issue early); dom-0 blocks early-exit. Lower VGPR -> more blocks/CU.
__global__ __launch_bounds__(256)
void fvae_fused(const float* __restrict__ eps,      // [B,512]
                const int*   __restrict__ dom_idx,  // [B]
                const float* __restrict__ L_emb,    // [16, NL]
                const float* __restrict__ S_emb,    // [16, 64]
                const float* __restrict__ bias_ns,  // [16, 64]
                const float* __restrict__ bias_sh,  // [448]
                float*       __restrict__ out)      // [B,512]
{
    const int b    = blockIdx.x;
    const int tid  = threadIdx.x;
    const int wave = tid >> 6;
    const int lane = tid & 63;

    __shared__ float y_s[KK];
    __shared__ float U_s[(KK * (KK - 1)) / 2];   // packed strictly-lower (7.9 KB)

    const int dom = dom_idx[b];
    const float* __restrict__ epsb = eps + (size_t)b * NTOT;
    float*       __restrict__ outb = out + (size_t)b * NTOT;

    if (dom == 0) {
        // L=0, S=I: out = eps + [bias_sh | bias_ns]. 128 float4 cols, tid<128.
        if (tid < 128) {
            const float4 e = *(const float4*)(epsb + tid * 4);
            float4 bv;
            if (tid < 112) bv = *(const float4*)(bias_sh + tid * 4);
            else           bv = *(const float4*)(bias_ns + (tid - 112) * 4);
            float4 o; o.x = e.x + bv.x; o.y = e.y + bv.y;
            o.z = e.z + bv.z; o.w = e.w + bv.w;
            *(float4*)(outb + tid * 4) = o;
        }
        return;
    }

    const float* __restrict__ Ld = L_emb + (size_t)dom * NL;

    // ---- eps direct to registers (coalesced; issued now, used after barrier)
    float er[7];
    #pragma unroll
    for (int k = 0; k < 7; ++k) er[k] = epsb[lane + 64 * k];

    if (wave == 0) {
        // ---- head write overlaps U staging: 112 float4 over 64 lanes
        for (int q = lane; q < NH / 4; q += 64) {
            const float4 e  = *(const float4*)(epsb + q * 4);
            const float4 bs = *(const float4*)(bias_sh + q * 4);
            float4 o; o.x = e.x + bs.x; o.y = e.y + bs.y;
            o.z = e.z + bs.z; o.w = e.w + bs.w;
            *(float4*)(outb + q * 4) = o;
        }
    } else {
        // ---- waves 1-3 stage packed U coalesced (r in {1,2,3}+3k covers 1..63)
        for (int r = wave; r < KK; r += 3)
            if (lane < r)
                U_s[(r * (r - 1)) / 2 + lane] =
                    Ld[r * NH + (r * (r - 1)) / 2 + NH + lane];
    }
    __syncthreads();

    // ---- phase 2: wave owns rows [wave*16, +16), 4 static batches of 4 rows
    #pragma unroll
    for (int bt = 0; bt < 4; ++bt) {
        const int r0 = wave * 16 + bt * 4;
        float a0, a1, a2, a3;
        {
            const float* __restrict__ T0 = Ld + (r0    ) * NH + ((r0    ) * (r0 - 1)) / 2;
            const float* __restrict__ T1 = Ld + (r0 + 1) * NH + ((r0 + 1) * (r0    )) / 2;
            const float* __restrict__ T2 = Ld + (r0 + 2) * NH + ((r0 + 2) * (r0 + 1)) / 2;
            const float* __restrict__ T3 = Ld + (r0 + 3) * NH + ((r0 + 3) * (r0 + 2)) / 2;
            a0 = T0[lane]*er[0] + T0[lane+64]*er[1] + T0[lane+128]*er[2]
               + T0[lane+192]*er[3] + T0[lane+256]*er[4] + T0[lane+320]*er[5]
               + T0[lane+384]*er[6];
            a1 = T1[lane]*er[0] + T1[lane+64]*er[1] + T1[lane+128]*er[2]
               + T1[lane+192]*er[3] + T1[lane+256]*er[4] + T1[lane+320]*er[5]
               + T1[lane+384]*er[6];
            a2 = T2[lane]*er[0] + T2[lane+64]*er[1] + T2[lane+128]*er[2]
               + T2[lane+192]*er[3] + T2[lane+256]*er[4] + T2[lane+320]*er[5]
               + T2[lane+384]*er[6];
            a3 = T3[lane]*er[0] + T3[lane+64]*er[1] + T3[lane+128]*er[2]
               + T3[lane+192]*er[3] + T3[lane+256]*er[4] + T3[lane+320]*er[5]
               + T3[lane+384]*er[6];
        }
        // merged butterfly reduce (r4-verified): lane g<4 holds sum of a_g
        a0 += __shfl_xor(a0, 1);  a1 += __shfl_xor(a1, 1);
        a2 += __shfl_xor(a2, 1);  a3 += __shfl_xor(a3, 1);
        float c0 = (lane & 1) ? a1 : a0;
        float c1 = (lane & 1) ? a3 : a2;
        c0 += __shfl_xor(c0, 2);  c1 += __shfl_xor(c1, 2);
        float dsum = (lane & 2) ? c1 : c0;
        dsum += __shfl_xor(dsum, 4);
        dsum += __shfl_xor(dsum, 8);
        dsum += __shfl_xor(dsum, 16);
        dsum += __shfl_xor(dsum, 32);
        if (lane < 4) {
            const int r = r0 + lane;
            y_s[r] = dsum + S_emb[dom * KK + r] * epsb[NH + r];
        }
    }
    __syncthreads();

    // ---- phase 3: wave 0 only; U_s read directly (addresses chain-independent
    // -> compiler issues ds_reads ahead of the serial fma chain)
    if (wave == 0) {
        const int m  = lane;
        const int tb = (m * (m - 1)) / 2;
        float z = y_s[m];
        #pragma unroll
        for (int r = 0; r < KK - 1; ++r) {
            const float u = (r < m) ? U_s[tb + r] : 0.f;
            z += u * __shfl(z, r);               // lane r's z final by step r
        }
        outb[NH + m] = z + bias_ns[dom * KK + m];
    }
}

extern "C" void kernel_launch(void* const* d_in, const int* in_sizes, int n_in,
                              void* d_out, int out_size, void* d_ws, size_t ws_size,
                              hipStream_t stream) {
    const float* eps     = (const float*)d_in[0];
    const int*   dom     = (const int*)  d_in[1];
    const float* L_emb   = (const float*)d_in[2];
    const float* S_emb   = (const float*)d_in[3];
    const float* bias_ns = (const float*)d_in[4];
    const float* bias_sh = (const float*)d_in[5];
    float* out = (float*)d_out;

    const int B = in_sizes[0] / NTOT;   // 1024
    fvae_fused<<<dim3(B), dim3(256), 0, stream>>>(eps, dom, L_emb, S_emb,
                                                  bias_ns, bias_sh, out);
}